// Round 4
// baseline (446.650 us; speedup 1.0000x reference)
//
#include <hip/hip_runtime.h>
#include <hip/hip_bf16.h>

// Problem dims
constexpr int Bn   = 8;
constexpr int Cin  = 576;
constexpr int Cc   = 192;
constexpr int Hh   = 56;
constexpr int Ww   = 56;
constexpr int HWn  = Hh * Ww;          // 3136
constexpr int CKK  = Cc * 9;           // 1728

// GEMM dims (batch folded into N)
constexpr int GM = 1792;               // 1728 padded
constexpr int GK = 576;
constexpr int GN = Bn * HWn;           // 25088

using f16x8 = __attribute__((ext_vector_type(8))) _Float16;
using f32x4 = __attribute__((ext_vector_type(4))) float;

__device__ __forceinline__ void async_copy16(void* lds, const void* gptr) {
    __builtin_amdgcn_global_load_lds(
        (const __attribute__((address_space(1))) unsigned int*)gptr,
        (__attribute__((address_space(3))) unsigned int*)lds, 16, 0, 0);
}

__device__ __forceinline__ float blo(unsigned int u) { return __uint_as_float(u << 16); }
__device__ __forceinline__ float bhi(unsigned int u) { return __uint_as_float(u & 0xffff0000u); }
__device__ __forceinline__ unsigned short bf16bits(float f) {
    union { __hip_bfloat16 h; unsigned short u; } c; c.h = __float2bfloat16(f); return c.u;
}

// ---------------------------------------------------------------------------
// fc_w (1728x576 f32) -> fcw16 (1792x576 f16, pad rows zero)
// ---------------------------------------------------------------------------
__global__ __launch_bounds__(256) void cast_fcw_kernel(
    const float* __restrict__ fcw, _Float16* __restrict__ out)
{
    int idx = blockIdx.x * 256 + threadIdx.x;
    int e = idx * 4;
    if (e >= GM * GK) return;
    int row = e / GK;
    union { ushort4 u; _Float16 h[4]; } pk;
    if (row < CKK) {
        float4 v = *(const float4*)&fcw[e];
        pk.h[0] = (_Float16)v.x; pk.h[1] = (_Float16)v.y;
        pk.h[2] = (_Float16)v.z; pk.h[3] = (_Float16)v.w;
    } else {
        pk.h[0] = pk.h[1] = pk.h[2] = pk.h[3] = (_Float16)0.f;
    }
    *(ushort4*)&out[e] = pk.u;
}

// ---------------------------------------------------------------------------
// x[b][k][hw] f32 -> xt[b*HW + hw][k] f16
// ---------------------------------------------------------------------------
__global__ __launch_bounds__(256) void transpose_cast_kernel(
    const float* __restrict__ x, _Float16* __restrict__ xt)
{
    __shared__ float t[32][65];
    const int b = blockIdx.z, k0 = blockIdx.y * 32, hw0 = blockIdx.x * 64;
    const int tid = threadIdx.x;
    const int col = tid & 63, kr = tid >> 6;
#pragma unroll
    for (int p = 0; p < 8; p++) {
        int k = kr + p * 4;
        t[k][col] = x[(size_t)(b * Cin + k0 + k) * HWn + hw0 + col];
    }
    __syncthreads();
    const int row = tid >> 2, cq = (tid & 3) * 8;
    union { uint4 u; _Float16 h[8]; } pk;
#pragma unroll
    for (int j = 0; j < 8; j++) pk.h[j] = (_Float16)t[cq + j][row];
    *(uint4*)&xt[(size_t)(b * HWn + hw0 + row) * GK + k0 + cq] = pk.u;
}

// ---------------------------------------------------------------------------
// MFMA GEMM: logits[b][m][hw] = sum_k fcw[m][k] * x[b][k][hw]  (bf16 out)
// XOR-swizzled LDS (conflict-free b128 reads); swapped-operand MFMA so each
// lane holds 4 consecutive hw -> packed dwordx2 stores.
// ---------------------------------------------------------------------------
__global__ __launch_bounds__(256) void gemm_mfma_kernel(
    const _Float16* __restrict__ A, const _Float16* __restrict__ Bm,
    __hip_bfloat16* __restrict__ logits)
{
    __shared__ _Float16 As[128 * 32];
    __shared__ _Float16 Bs[128 * 32];

    const int tid = threadIdx.x;
    const int n0 = blockIdx.x * 128;
    const int m0 = blockIdx.y * 128;
    const int lane = tid & 63;
    const int wave = tid >> 6;
    const int wm = (wave >> 1) * 64;
    const int wn = (wave & 1) * 64;
    const int lm = lane & 15;
    const int lc = lane >> 4;           // logical k-chunk (8 f16 = 16B)

    // Loader: thread t fills physical chunk t (16B): row r=t>>2, phys chunk t&3.
    // That slot stores logical k-chunk (t&3) ^ ((r>>1)&3) = (t&3) ^ ((t>>3)&3).
    const int lrow = tid >> 2;
    const int koff = (((tid & 3) ^ ((tid >> 3) & 3)) << 3);  // f16 units

    // Reader LDS offsets (f16 units), invariant across k-loop.
    int offA[4], offB[4];
#pragma unroll
    for (int i = 0; i < 4; i++) {
        int ra = wm + i * 16 + lm;
        offA[i] = ra * 32 + ((lc ^ ((ra >> 1) & 3)) << 3);
        int rb = wn + i * 16 + lm;
        offB[i] = rb * 32 + ((lc ^ ((rb >> 1) & 3)) << 3);
    }

    f32x4 acc[4][4] = {};

    for (int k0 = 0; k0 < GK; k0 += 32) {
        async_copy16(&As[(size_t)tid * 8],        &A[(size_t)(m0 + lrow) * GK + k0 + koff]);
        async_copy16(&As[2048 + (size_t)tid * 8], &A[(size_t)(m0 + 64 + lrow) * GK + k0 + koff]);
        async_copy16(&Bs[(size_t)tid * 8],        &Bm[(size_t)(n0 + lrow) * GK + k0 + koff]);
        async_copy16(&Bs[2048 + (size_t)tid * 8], &Bm[(size_t)(n0 + 64 + lrow) * GK + k0 + koff]);
        __syncthreads();
        f16x8 af[4], bf[4];
#pragma unroll
        for (int i = 0; i < 4; i++) {
            af[i] = *(const f16x8*)&As[offA[i]];
            bf[i] = *(const f16x8*)&Bs[offB[i]];
        }
#pragma unroll
        for (int i = 0; i < 4; i++)
#pragma unroll
            for (int j = 0; j < 4; j++)
                // swapped operands: D rows = n (bf), cols = m (af)
                acc[i][j] = __builtin_amdgcn_mfma_f32_16x16x32_f16(bf[j], af[i], acc[i][j], 0, 0, 0);
        __syncthreads();
    }

    // Epilogue: lane holds 4 consecutive n (hw) for m = m0+wm+i*16+lm.
    const int mcol = m0 + wm + lm;
#pragma unroll
    for (int i = 0; i < 4; i++) {
        int m = mcol + i * 16;
        if (m >= CKK) continue;
#pragma unroll
        for (int j = 0; j < 4; j++) {
            int n = n0 + wn + j * 16 + lc * 4;   // 4 consecutive n, same batch
            int b = n / HWn, hw = n - b * HWn;
            uint2 pk;
            pk.x = (unsigned)bf16bits(acc[i][j][0]) | ((unsigned)bf16bits(acc[i][j][1]) << 16);
            pk.y = (unsigned)bf16bits(acc[i][j][2]) | ((unsigned)bf16bits(acc[i][j][3]) << 16);
            *(uint2*)&logits[((size_t)b * CKK + m) * HWn + hw] = pk;
        }
    }
}

// ---------------------------------------------------------------------------
// conv1: feat[i][b][c][h][w] = relu(sum_{d,u,v} x[b][3c+d][h+u-1][w+v-1]*w1[i][c][d][u][v])
// 28-row tile; thread = 8-px row strip; window in VGPRs; weights s_loaded;
// 16B packed stores.
// ---------------------------------------------------------------------------
__global__ __launch_bounds__(256, 3) void conv1_kernel(
    const float* __restrict__ x, const float* __restrict__ w1,
    __hip_bfloat16* __restrict__ feat)
{
    const int c = blockIdx.x, hb = blockIdx.y, b = blockIdx.z;
    const int tid = threadIdx.x;
    const int h0 = hb * 28;
    __shared__ float xt[3][30][60];   // col = w+1 (cols 0..57 used)

    for (int idx = tid; idx < 1260; idx += 256) {
        int d = idx / 420, rem = idx - d * 420;
        int r = rem / 14, g = rem - r * 14;
        int h = h0 - 1 + r;
        float4 v = {0.f, 0.f, 0.f, 0.f};
        if (h >= 0 && h < Hh)
            v = *(const float4*)&x[((size_t)(b * Cin + 3 * c + d) * Hh + h) * Ww + 4 * g];
        xt[d][r][1 + 4 * g + 0] = v.x;
        xt[d][r][1 + 4 * g + 1] = v.y;
        xt[d][r][1 + 4 * g + 2] = v.z;
        xt[d][r][1 + 4 * g + 3] = v.w;
    }
    for (int idx = tid; idx < 180; idx += 256) {
        int d = idx / 60, rem = idx - d * 60;
        int r = rem >> 1, col = (rem & 1) ? 57 : 0;
        xt[d][r][col] = 0.f;
    }
    __syncthreads();

    if (tid < 196) {
        const int row = tid / 7, seg = tid - (tid / 7) * 7;
        const int w0 = seg * 8;

        float win[3][3][10];
#pragma unroll
        for (int d = 0; d < 3; d++)
#pragma unroll
            for (int u = 0; u < 3; u++)
#pragma unroll
                for (int k = 0; k < 10; k++)
                    win[d][u][k] = xt[d][row + u][w0 + k];

        const int hw = (h0 + row) * Ww + w0;
#pragma unroll 1
        for (int i = 0; i < 9; i++) {
            const float* wp = w1 + ((size_t)i * Cc + c) * 27;
            float wgt[27];
#pragma unroll
            for (int j = 0; j < 27; j++) wgt[j] = wp[j];
            float acc[8] = {};
#pragma unroll
            for (int d = 0; d < 3; d++)
#pragma unroll
                for (int u = 0; u < 3; u++)
#pragma unroll
                    for (int v = 0; v < 3; v++) {
                        float wv = wgt[d * 9 + u * 3 + v];
#pragma unroll
                        for (int p = 0; p < 8; p++)
                            acc[p] += win[d][u][p + v] * wv;
                    }
            uint4 pk;
            pk.x = (unsigned)bf16bits(fmaxf(acc[0], 0.f)) | ((unsigned)bf16bits(fmaxf(acc[1], 0.f)) << 16);
            pk.y = (unsigned)bf16bits(fmaxf(acc[2], 0.f)) | ((unsigned)bf16bits(fmaxf(acc[3], 0.f)) << 16);
            pk.z = (unsigned)bf16bits(fmaxf(acc[4], 0.f)) | ((unsigned)bf16bits(fmaxf(acc[5], 0.f)) << 16);
            pk.w = (unsigned)bf16bits(fmaxf(acc[6], 0.f)) | ((unsigned)bf16bits(fmaxf(acc[7], 0.f)) << 16);
            *(uint4*)&feat[(((size_t)i * Bn + b) * Cc + c) * HWn + hw] = pk;
        }
    }
}

// ---------------------------------------------------------------------------
// conv2 + softmax + aggregation. Thread = 8-px row strip; ft tile stride 72.
// ---------------------------------------------------------------------------
__global__ __launch_bounds__(256, 3) void conv2_agg_kernel(
    const __hip_bfloat16* __restrict__ feat,
    const __hip_bfloat16* __restrict__ logits,
    const float* __restrict__ w2, float* __restrict__ out)
{
    const int c = blockIdx.x, hb = blockIdx.y, b = blockIdx.z;
    const int tid = threadIdx.x;
    const int h0 = hb * 28;
    __shared__ unsigned short ft[9][30][72];   // col = w+2 (cols 0..59 used)

    for (int idx = tid; idx < 1890; idx += 256) {
        int i = idx / 210, rem = idx - i * 210;
        int r = rem / 7, g = rem - r * 7;
        int h = h0 - 1 + r;
        uint4 v = {0u, 0u, 0u, 0u};
        if (h >= 0 && h < Hh)
            v = *(const uint4*)&feat[(((size_t)i * Bn + b) * Cc + c) * HWn + h * Ww + 8 * g];
        unsigned int* dst = (unsigned int*)&ft[i][r][2 + 8 * g];
        dst[0] = v.x; dst[1] = v.y; dst[2] = v.z; dst[3] = v.w;
    }
    for (int idx = tid; idx < 1080; idx += 256) {
        int i = idx / 120, rem = idx - i * 120;
        int r = rem >> 2, e = rem & 3;
        int col = (e < 2) ? e : 56 + e;
        ft[i][r][col] = 0;
    }
    __syncthreads();

    if (tid < 196) {
        const int row = tid / 7, seg = tid - (tid / 7) * 7;
        const int w0 = 8 * seg;
        const int hw = (h0 + row) * Ww + w0;

        float lg[9][8];
        const __hip_bfloat16* lbase = logits + ((size_t)b * CKK + c * 9) * HWn + hw;
#pragma unroll
        for (int i = 0; i < 9; i++) {
            uint4 lv = *(const uint4*)&lbase[(size_t)i * HWn];
            lg[i][0] = blo(lv.x); lg[i][1] = bhi(lv.x);
            lg[i][2] = blo(lv.y); lg[i][3] = bhi(lv.y);
            lg[i][4] = blo(lv.z); lg[i][5] = bhi(lv.z);
            lg[i][6] = blo(lv.w); lg[i][7] = bhi(lv.w);
        }
        float mx[8], sum[8];
#pragma unroll
        for (int p = 0; p < 8; p++) {
            mx[p] = lg[0][p];
#pragma unroll
            for (int i = 1; i < 9; i++) mx[p] = fmaxf(mx[p], lg[i][p]);
            sum[p] = 0.f;
        }
#pragma unroll
        for (int i = 0; i < 9; i++)
#pragma unroll
            for (int p = 0; p < 8; p++) {
                lg[i][p] = __expf(lg[i][p] - mx[p]);
                sum[p] += lg[i][p];
            }

        float oacc[8] = {};
#pragma unroll 1
        for (int i = 0; i < 9; i++) {
            const float* wp = w2 + ((size_t)i * Cc + c) * 9;
            float wgt[9];
#pragma unroll
            for (int j = 0; j < 9; j++) wgt[j] = wp[j];
            float cacc[8] = {};
#pragma unroll
            for (int u = 0; u < 3; u++) {
                const unsigned short* fr = &ft[i][row + u][w0];
                uint4 a = *(const uint4*)fr;
                uint2 bq = *(const uint2*)(fr + 8);
                float wf[11];
                wf[1] = bhi(a.x);
                wf[2] = blo(a.y);  wf[3] = bhi(a.y);
                wf[4] = blo(a.z);  wf[5] = bhi(a.z);
                wf[6] = blo(a.w);  wf[7] = bhi(a.w);
                wf[8] = blo(bq.x); wf[9] = bhi(bq.x);
                wf[10] = blo(bq.y);
#pragma unroll
                for (int v = 0; v < 3; v++) {
                    float wv = wgt[u * 3 + v];
#pragma unroll
                    for (int p = 0; p < 8; p++)
                        cacc[p] += wf[p + v + 1] * wv;
                }
            }
#pragma unroll
            for (int p = 0; p < 8; p++) oacc[p] += cacc[p] * lg[i][p];
        }

        float* obase = out + ((size_t)(b * Cc + c)) * HWn + hw;
        float4 o0, o1;
        o0.x = oacc[0] * __builtin_amdgcn_rcpf(sum[0]);
        o0.y = oacc[1] * __builtin_amdgcn_rcpf(sum[1]);
        o0.z = oacc[2] * __builtin_amdgcn_rcpf(sum[2]);
        o0.w = oacc[3] * __builtin_amdgcn_rcpf(sum[3]);
        o1.x = oacc[4] * __builtin_amdgcn_rcpf(sum[4]);
        o1.y = oacc[5] * __builtin_amdgcn_rcpf(sum[5]);
        o1.z = oacc[6] * __builtin_amdgcn_rcpf(sum[6]);
        o1.w = oacc[7] * __builtin_amdgcn_rcpf(sum[7]);
        *(float4*)&obase[0] = o0;
        *(float4*)&obase[4] = o1;
    }
}

// ---------------------------------------------------------------------------
extern "C" void kernel_launch(void* const* d_in, const int* in_sizes, int n_in,
                              void* d_out, int out_size, void* d_ws, size_t ws_size,
                              hipStream_t stream)
{
    const float* x    = (const float*)d_in[0];
    const float* fc_w = (const float*)d_in[1];
    const float* w1   = (const float*)d_in[2];
    const float* w2   = (const float*)d_in[3];
    float* out = (float*)d_out;

    char* ws = (char*)d_ws;
    __hip_bfloat16* logits = (__hip_bfloat16*)ws;
    char* region2 = ws + (size_t)Bn * CKK * HWn * 2;
    __hip_bfloat16* feat = (__hip_bfloat16*)region2;
    _Float16* xt    = (_Float16*)region2;
    _Float16* fcw16 = (_Float16*)(region2 + (size_t)GN * GK * 2);

    cast_fcw_kernel<<<(GM * GK / 4 + 255) / 256, 256, 0, stream>>>(fc_w, fcw16);
    transpose_cast_kernel<<<dim3(HWn / 64, GK / 32, Bn), 256, 0, stream>>>(x, xt);
    gemm_mfma_kernel<<<dim3(GN / 128, GM / 128), 256, 0, stream>>>(fcw16, xt, logits);
    conv1_kernel<<<dim3(Cc, 2, Bn), 256, 0, stream>>>(x, w1, feat);
    conv2_agg_kernel<<<dim3(Cc, 2, Bn), 256, 0, stream>>>(feat, logits, w2, out);
}

// Round 5
// 306.037 us; speedup vs baseline: 1.4595x; 1.4595x over previous
//
#include <hip/hip_runtime.h>
#include <hip/hip_bf16.h>

// Problem dims
constexpr int Bn   = 8;
constexpr int Cin  = 576;
constexpr int Cc   = 192;
constexpr int Hh   = 56;
constexpr int Ww   = 56;
constexpr int HWn  = Hh * Ww;          // 3136
constexpr int CKK  = Cc * 9;           // 1728

// GEMM dims (batch folded into N)
constexpr int GM = 1792;               // 1728 padded
constexpr int GK = 576;
constexpr int GN = Bn * HWn;           // 25088

using f16x8 = __attribute__((ext_vector_type(8))) _Float16;
using f32x4 = __attribute__((ext_vector_type(4))) float;

__device__ __forceinline__ void async_copy16(void* lds, const void* gptr) {
    __builtin_amdgcn_global_load_lds(
        (const __attribute__((address_space(1))) unsigned int*)gptr,
        (__attribute__((address_space(3))) unsigned int*)lds, 16, 0, 0);
}

__device__ __forceinline__ float blo(unsigned int u) { return __uint_as_float(u << 16); }
__device__ __forceinline__ float bhi(unsigned int u) { return __uint_as_float(u & 0xffff0000u); }
__device__ __forceinline__ unsigned short bf16bits(float f) {
    union { __hip_bfloat16 h; unsigned short u; } c; c.h = __float2bfloat16(f); return c.u;
}

// ---------------------------------------------------------------------------
// fc_w (1728x576 f32) -> fcw16 (1792x576 f16, pad rows zero)
// ---------------------------------------------------------------------------
__global__ __launch_bounds__(256) void cast_fcw_kernel(
    const float* __restrict__ fcw, _Float16* __restrict__ out)
{
    int idx = blockIdx.x * 256 + threadIdx.x;
    int e = idx * 4;
    if (e >= GM * GK) return;
    int row = e / GK;
    union { ushort4 u; _Float16 h[4]; } pk;
    if (row < CKK) {
        float4 v = *(const float4*)&fcw[e];
        pk.h[0] = (_Float16)v.x; pk.h[1] = (_Float16)v.y;
        pk.h[2] = (_Float16)v.z; pk.h[3] = (_Float16)v.w;
    } else {
        pk.h[0] = pk.h[1] = pk.h[2] = pk.h[3] = (_Float16)0.f;
    }
    *(ushort4*)&out[e] = pk.u;
}

// ---------------------------------------------------------------------------
// x[b][k][hw] f32 -> xt[b*HW + hw][k] f16
// ---------------------------------------------------------------------------
__global__ __launch_bounds__(256) void transpose_cast_kernel(
    const float* __restrict__ x, _Float16* __restrict__ xt)
{
    __shared__ float t[32][65];
    const int b = blockIdx.z, k0 = blockIdx.y * 32, hw0 = blockIdx.x * 64;
    const int tid = threadIdx.x;
    const int col = tid & 63, kr = tid >> 6;
#pragma unroll
    for (int p = 0; p < 8; p++) {
        int k = kr + p * 4;
        t[k][col] = x[(size_t)(b * Cin + k0 + k) * HWn + hw0 + col];
    }
    __syncthreads();
    const int row = tid >> 2, cq = (tid & 3) * 8;
    union { uint4 u; _Float16 h[8]; } pk;
#pragma unroll
    for (int j = 0; j < 8; j++) pk.h[j] = (_Float16)t[cq + j][row];
    *(uint4*)&xt[(size_t)(b * HWn + hw0 + row) * GK + k0 + cq] = pk.u;
}

// ---------------------------------------------------------------------------
// MFMA GEMM: logits[b][m][hw] = sum_k fcw[m][k] * x[b][k][hw]  (bf16 out)
// XOR-swizzled LDS (conflict-free b128 reads); swapped-operand MFMA so each
// lane holds 4 consecutive hw -> packed dwordx2 stores.
// ---------------------------------------------------------------------------
__global__ __launch_bounds__(256) void gemm_mfma_kernel(
    const _Float16* __restrict__ A, const _Float16* __restrict__ Bm,
    __hip_bfloat16* __restrict__ logits)
{
    __shared__ _Float16 As[128 * 32];
    __shared__ _Float16 Bs[128 * 32];

    const int tid = threadIdx.x;
    const int n0 = blockIdx.x * 128;
    const int m0 = blockIdx.y * 128;
    const int lane = tid & 63;
    const int wave = tid >> 6;
    const int wm = (wave >> 1) * 64;
    const int wn = (wave & 1) * 64;
    const int lm = lane & 15;
    const int lc = lane >> 4;           // logical k-chunk (8 f16 = 16B)

    // Loader: thread t fills physical chunk t (16B): row r=t>>2, phys chunk t&3.
    // That slot stores logical k-chunk (t&3) ^ ((r>>1)&3).
    const int lrow = tid >> 2;
    const int koff = (((tid & 3) ^ ((tid >> 3) & 3)) << 3);  // f16 units

    int offA[4], offB[4];
#pragma unroll
    for (int i = 0; i < 4; i++) {
        int ra = wm + i * 16 + lm;
        offA[i] = ra * 32 + ((lc ^ ((ra >> 1) & 3)) << 3);
        int rb = wn + i * 16 + lm;
        offB[i] = rb * 32 + ((lc ^ ((rb >> 1) & 3)) << 3);
    }

    f32x4 acc[4][4] = {};

    for (int k0 = 0; k0 < GK; k0 += 32) {
        async_copy16(&As[(size_t)tid * 8],        &A[(size_t)(m0 + lrow) * GK + k0 + koff]);
        async_copy16(&As[2048 + (size_t)tid * 8], &A[(size_t)(m0 + 64 + lrow) * GK + k0 + koff]);
        async_copy16(&Bs[(size_t)tid * 8],        &Bm[(size_t)(n0 + lrow) * GK + k0 + koff]);
        async_copy16(&Bs[2048 + (size_t)tid * 8], &Bm[(size_t)(n0 + 64 + lrow) * GK + k0 + koff]);
        __syncthreads();
        f16x8 af[4], bf[4];
#pragma unroll
        for (int i = 0; i < 4; i++) {
            af[i] = *(const f16x8*)&As[offA[i]];
            bf[i] = *(const f16x8*)&Bs[offB[i]];
        }
#pragma unroll
        for (int i = 0; i < 4; i++)
#pragma unroll
            for (int j = 0; j < 4; j++)
                acc[i][j] = __builtin_amdgcn_mfma_f32_16x16x32_f16(bf[j], af[i], acc[i][j], 0, 0, 0);
        __syncthreads();
    }

    const int mcol = m0 + wm + lm;
#pragma unroll
    for (int i = 0; i < 4; i++) {
        int m = mcol + i * 16;
        if (m >= CKK) continue;
#pragma unroll
        for (int j = 0; j < 4; j++) {
            int n = n0 + wn + j * 16 + lc * 4;   // 4 consecutive n, same batch
            int b = n / HWn, hw = n - b * HWn;
            uint2 pk;
            pk.x = (unsigned)bf16bits(acc[i][j][0]) | ((unsigned)bf16bits(acc[i][j][1]) << 16);
            pk.y = (unsigned)bf16bits(acc[i][j][2]) | ((unsigned)bf16bits(acc[i][j][3]) << 16);
            *(uint2*)&logits[((size_t)b * CKK + m) * HWn + hw] = pk;
        }
    }
}

// ---------------------------------------------------------------------------
// conv1: feat[i][b][c][h][w] = relu(sum_{d,u,v} x[b][3c+d][h+u-1][w+v-1]*w1[i][c][d][u][v])
// 28-row tile; thread = 8-px row strip; window in VGPRs; weights s_loaded.
// ---------------------------------------------------------------------------
__global__ __launch_bounds__(256, 3) void conv1_kernel(
    const float* __restrict__ x, const float* __restrict__ w1,
    __hip_bfloat16* __restrict__ feat)
{
    const int c = blockIdx.x, hb = blockIdx.y, b = blockIdx.z;
    const int tid = threadIdx.x;
    const int h0 = hb * 28;
    __shared__ float xt[3][30][60];   // col = w+1 (cols 0..57 used)

    for (int idx = tid; idx < 1260; idx += 256) {
        int d = idx / 420, rem = idx - d * 420;
        int r = rem / 14, g = rem - r * 14;
        int h = h0 - 1 + r;
        float4 v = {0.f, 0.f, 0.f, 0.f};
        if (h >= 0 && h < Hh)
            v = *(const float4*)&x[((size_t)(b * Cin + 3 * c + d) * Hh + h) * Ww + 4 * g];
        xt[d][r][1 + 4 * g + 0] = v.x;
        xt[d][r][1 + 4 * g + 1] = v.y;
        xt[d][r][1 + 4 * g + 2] = v.z;
        xt[d][r][1 + 4 * g + 3] = v.w;
    }
    for (int idx = tid; idx < 180; idx += 256) {
        int d = idx / 60, rem = idx - d * 60;
        int r = rem >> 1, col = (rem & 1) ? 57 : 0;
        xt[d][r][col] = 0.f;
    }
    __syncthreads();

    if (tid < 196) {
        const int row = tid / 7, seg = tid - (tid / 7) * 7;
        const int w0 = seg * 8;

        float win[3][3][10];
#pragma unroll
        for (int d = 0; d < 3; d++)
#pragma unroll
            for (int u = 0; u < 3; u++)
#pragma unroll
                for (int k = 0; k < 10; k++)
                    win[d][u][k] = xt[d][row + u][w0 + k];

        const int hw = (h0 + row) * Ww + w0;
#pragma unroll 1
        for (int i = 0; i < 9; i++) {
            const float* wp = w1 + ((size_t)i * Cc + c) * 27;
            float wgt[27];
#pragma unroll
            for (int j = 0; j < 27; j++) wgt[j] = wp[j];
            float acc[8] = {};
#pragma unroll
            for (int d = 0; d < 3; d++)
#pragma unroll
                for (int u = 0; u < 3; u++)
#pragma unroll
                    for (int v = 0; v < 3; v++) {
                        float wv = wgt[d * 9 + u * 3 + v];
#pragma unroll
                        for (int p = 0; p < 8; p++)
                            acc[p] += win[d][u][p + v] * wv;
                    }
            uint4 pk;
            pk.x = (unsigned)bf16bits(fmaxf(acc[0], 0.f)) | ((unsigned)bf16bits(fmaxf(acc[1], 0.f)) << 16);
            pk.y = (unsigned)bf16bits(fmaxf(acc[2], 0.f)) | ((unsigned)bf16bits(fmaxf(acc[3], 0.f)) << 16);
            pk.z = (unsigned)bf16bits(fmaxf(acc[4], 0.f)) | ((unsigned)bf16bits(fmaxf(acc[5], 0.f)) << 16);
            pk.w = (unsigned)bf16bits(fmaxf(acc[6], 0.f)) | ((unsigned)bf16bits(fmaxf(acc[7], 0.f)) << 16);
            *(uint4*)&feat[(((size_t)i * Bn + b) * Cc + c) * HWn + hw] = pk;
        }
    }
}

// ---------------------------------------------------------------------------
// conv2 + softmax + aggregation. Thread = 8-px row strip; ft tile stride 72.
// i-loop FULLY UNROLLED: lg[9][8] must stay statically indexed (VGPRs) —
// a rolled loop demotes it to scratch (R4: 322 MB HBM writes, 2x slowdown).
// ---------------------------------------------------------------------------
__global__ __launch_bounds__(256, 3) void conv2_agg_kernel(
    const __hip_bfloat16* __restrict__ feat,
    const __hip_bfloat16* __restrict__ logits,
    const float* __restrict__ w2, float* __restrict__ out)
{
    const int c = blockIdx.x, hb = blockIdx.y, b = blockIdx.z;
    const int tid = threadIdx.x;
    const int h0 = hb * 28;
    __shared__ unsigned short ft[9][30][72];   // col = w+2 (cols 0..59 used)

    for (int idx = tid; idx < 1890; idx += 256) {
        int i = idx / 210, rem = idx - i * 210;
        int r = rem / 7, g = rem - r * 7;
        int h = h0 - 1 + r;
        uint4 v = {0u, 0u, 0u, 0u};
        if (h >= 0 && h < Hh)
            v = *(const uint4*)&feat[(((size_t)i * Bn + b) * Cc + c) * HWn + h * Ww + 8 * g];
        unsigned int* dst = (unsigned int*)&ft[i][r][2 + 8 * g];
        dst[0] = v.x; dst[1] = v.y; dst[2] = v.z; dst[3] = v.w;
    }
    for (int idx = tid; idx < 1080; idx += 256) {
        int i = idx / 120, rem = idx - i * 120;
        int r = rem >> 2, e = rem & 3;
        int col = (e < 2) ? e : 56 + e;
        ft[i][r][col] = 0;
    }
    __syncthreads();

    if (tid < 196) {
        const int row = tid / 7, seg = tid - (tid / 7) * 7;
        const int w0 = 8 * seg;
        const int hw = (h0 + row) * Ww + w0;

        // ---- softmax over 9 positions, 8 px; normalized in-place ----
        float lg[9][8];
        const __hip_bfloat16* lbase = logits + ((size_t)b * CKK + c * 9) * HWn + hw;
#pragma unroll
        for (int i = 0; i < 9; i++) {
            uint4 lv = *(const uint4*)&lbase[(size_t)i * HWn];
            lg[i][0] = blo(lv.x); lg[i][1] = bhi(lv.x);
            lg[i][2] = blo(lv.y); lg[i][3] = bhi(lv.y);
            lg[i][4] = blo(lv.z); lg[i][5] = bhi(lv.z);
            lg[i][6] = blo(lv.w); lg[i][7] = bhi(lv.w);
        }
#pragma unroll
        for (int p = 0; p < 8; p++) {
            float mx = lg[0][p];
#pragma unroll
            for (int i = 1; i < 9; i++) mx = fmaxf(mx, lg[i][p]);
            float sum = 0.f;
#pragma unroll
            for (int i = 0; i < 9; i++) { lg[i][p] = __expf(lg[i][p] - mx); sum += lg[i][p]; }
            float inv = __builtin_amdgcn_rcpf(sum);
#pragma unroll
            for (int i = 0; i < 9; i++) lg[i][p] *= inv;
        }

        // ---- conv2 + weighted aggregation (i fully unrolled) ----
        float oacc[8] = {};
#pragma unroll
        for (int i = 0; i < 9; i++) {
            const float* wp = w2 + ((size_t)i * Cc + c) * 9;
            float wgt[9];
#pragma unroll
            for (int j = 0; j < 9; j++) wgt[j] = wp[j];
            float cacc[8] = {};
#pragma unroll
            for (int u = 0; u < 3; u++) {
                const unsigned short* fr = &ft[i][row + u][w0];
                uint4 a = *(const uint4*)fr;
                uint2 bq = *(const uint2*)(fr + 8);
                float wf[11];
                wf[1] = bhi(a.x);
                wf[2] = blo(a.y);  wf[3] = bhi(a.y);
                wf[4] = blo(a.z);  wf[5] = bhi(a.z);
                wf[6] = blo(a.w);  wf[7] = bhi(a.w);
                wf[8] = blo(bq.x); wf[9] = bhi(bq.x);
                wf[10] = blo(bq.y);
#pragma unroll
                for (int v = 0; v < 3; v++) {
                    float wv = wgt[u * 3 + v];
#pragma unroll
                    for (int p = 0; p < 8; p++)
                        cacc[p] += wf[p + v + 1] * wv;
                }
            }
#pragma unroll
            for (int p = 0; p < 8; p++) oacc[p] += cacc[p] * lg[i][p];
        }

        float* obase = out + ((size_t)(b * Cc + c)) * HWn + hw;
        float4 o0, o1;
        o0.x = oacc[0]; o0.y = oacc[1]; o0.z = oacc[2]; o0.w = oacc[3];
        o1.x = oacc[4]; o1.y = oacc[5]; o1.z = oacc[6]; o1.w = oacc[7];
        *(float4*)&obase[0] = o0;
        *(float4*)&obase[4] = o1;
    }
}

// ---------------------------------------------------------------------------
extern "C" void kernel_launch(void* const* d_in, const int* in_sizes, int n_in,
                              void* d_out, int out_size, void* d_ws, size_t ws_size,
                              hipStream_t stream)
{
    const float* x    = (const float*)d_in[0];
    const float* fc_w = (const float*)d_in[1];
    const float* w1   = (const float*)d_in[2];
    const float* w2   = (const float*)d_in[3];
    float* out = (float*)d_out;

    char* ws = (char*)d_ws;
    __hip_bfloat16* logits = (__hip_bfloat16*)ws;
    char* region2 = ws + (size_t)Bn * CKK * HWn * 2;
    __hip_bfloat16* feat = (__hip_bfloat16*)region2;
    _Float16* xt    = (_Float16*)region2;
    _Float16* fcw16 = (_Float16*)(region2 + (size_t)GN * GK * 2);

    cast_fcw_kernel<<<(GM * GK / 4 + 255) / 256, 256, 0, stream>>>(fc_w, fcw16);
    transpose_cast_kernel<<<dim3(HWn / 64, GK / 32, Bn), 256, 0, stream>>>(x, xt);
    gemm_mfma_kernel<<<dim3(GN / 128, GM / 128), 256, 0, stream>>>(fcw16, xt, logits);
    conv1_kernel<<<dim3(Cc, 2, Bn), 256, 0, stream>>>(x, w1, feat);
    conv2_agg_kernel<<<dim3(Cc, 2, Bn), 256, 0, stream>>>(feat, logits, w2, out);
}